// Round 3
// baseline (876.845 us; speedup 1.0000x reference)
//
#include <hip/hip_runtime.h>
#include <hip/hip_fp16.h>
#include <cstddef>

// Problem dims
#define CI_  64
#define CO_  256
#define DD_  31
#define HH_  96
#define WW_  96
#define HW_  (HH_*WW_)      // 9216
#define DHW_ (DD_*HW_)      // 285696
#define EPSV 1e-5f

// Conv tiling: block tile M=128 spatial (4h x 32w) x N=256 co, 4 waves
#define TLH 4
#define TLW 32
#define CIC 32              // ci chunk
// LDS halo layout strides in halves: xh[dd][row][cig(4)][col(34)][ci8(8)]
#define S_COL 8
#define S_CIG 272           // 34*8
#define S_ROW 1088          // 4*272
#define S_DD  6528          // 6*1088
#define XH_N  19584         // 3*6528 halves = 39168 B
// Epilogue transpose region (re-uses xh): per-wave 32co x (128sp+8pad) halves
#define EP_COSTRIDE 136
#define EP_WAVE     4352    // 32*136 halves = 8704 B

typedef _Float16 half8   __attribute__((ext_vector_type(8)));
typedef _Float16 half4v  __attribute__((ext_vector_type(4)));
typedef _Float16 half2v  __attribute__((ext_vector_type(2)));
typedef float    float4v __attribute__((ext_vector_type(4)));
typedef float    float2v __attribute__((ext_vector_type(2)));

// -------- weight repack: w[co][ci][kd][kh][kw] fp32 -> wr[t][co][ci] fp16 --------
__global__ __launch_bounds__(256) void repack_w_k(const float* __restrict__ w,
                                                  _Float16* __restrict__ wr) {
  int idx = blockIdx.x * 256 + threadIdx.x;   // 27*256*64 = 442368
  if (idx >= 27 * 256 * 64) return;
  int ci = idx & 63;
  int co = (idx >> 6) & 255;
  int t  = idx >> 14;
  wr[idx] = (_Float16)w[co * 1728 + ci * 27 + t];
}

// -------- conv3d (implicit GEMM, f16 MFMA) + BN + activation -> fp16 gates ------
// grid: x = 72 (24 h-tiles * 3 w-tiles), y = 31 (d). block 256 = 4 waves.
// wave w computes all 128 spatial x co [64w..64w+63] -> one gate group per wave.
__global__ __launch_bounds__(256, 2) void conv_mfma_k(
    const float* __restrict__ x, const _Float16* __restrict__ wr,
    const float* __restrict__ gamma, const float* __restrict__ beta,
    const float* __restrict__ mean, const float* __restrict__ var,
    _Float16* __restrict__ gates)
{
  __shared__ _Float16 xh[XH_N];

  const int wti = blockIdx.x % 3;
  const int hti = blockIdx.x / 3;
  const int d   = blockIdx.y;
  const int h0  = hti * TLH, w0 = wti * TLW;

  const int tid  = threadIdx.x;
  const int lane = tid & 63;
  const int wave = __builtin_amdgcn_readfirstlane(tid >> 6);
  const int lw   = lane & 15;    // A: m(spatial-w)  B: n(co)
  const int cig  = lane >> 4;    // k-group (8 consecutive ci)
  const int quad = lane >> 4;

  float4v acc[8][4];
#pragma unroll
  for (int m = 0; m < 8; m++)
#pragma unroll
    for (int j = 0; j < 4; j++) acc[m][j] = (float4v)0.f;

  for (int cc = 0; cc < CI_; cc += CIC) {
    __syncthreads();
    // ---- stage halo tile, fp32->fp16, transpose to ci-innermost ----
    for (int i = tid; i < 3 * 6 * 34 * 8; i += 256) {
      int cg4 = i / 612;                 // 0..7 (ci quad)
      int r   = i - cg4 * 612;
      int dd  = r / 204;
      int r2  = r - dd * 204;
      int row = r2 / 34;
      int col = r2 - row * 34;
      int gd = d + dd - 1, gh = h0 + row - 1, gw = w0 + col - 1;
      bool ok = (unsigned)gd < (unsigned)DD_ && (unsigned)gh < (unsigned)HH_ &&
                (unsigned)gw < (unsigned)WW_;
      const float* xp = x + (size_t)(cc + cg4 * 4) * DHW_ + gd * HW_ + gh * WW_ + gw;
      half4v hv;
#pragma unroll
      for (int j = 0; j < 4; j++)
        hv[j] = ok ? (_Float16)xp[(size_t)j * DHW_] : (_Float16)0.f;
      int a = dd * S_DD + row * S_ROW + (cg4 >> 1) * S_CIG + col * S_COL + (cg4 & 1) * 4;
      *(half4v*)(xh + a) = hv;
    }
    __syncthreads();

    // ---- K-loop over 27 taps, B-frags software double-buffered ----
    const _Float16* bp0 = wr + ((size_t)(wave * 64 + lw)) * 64 + cc + cig * 8;
    half8 bcur[4], bnxt[4];
#pragma unroll
    for (int j = 0; j < 4; j++) bcur[j] = *(const half8*)(bp0 + (size_t)j * 1024);
#pragma unroll 1
    for (int t = 0; t < 27; t++) {
      if (t < 26) {
        const _Float16* bpn = bp0 + (size_t)(t + 1) * 16384;
#pragma unroll
        for (int j = 0; j < 4; j++) bnxt[j] = *(const half8*)(bpn + (size_t)j * 1024);
      }
      const int kd = t / 9;
      const int rm = t - kd * 9;
      const int kh = rm / 3;
      const int kw = rm - kh * 3;
      const int abase = kd * S_DD + kh * S_ROW + cig * S_CIG + (lw + kw) * S_COL;
      half8 af[8];
#pragma unroll
      for (int m = 0; m < 8; m++)
        af[m] = *(const half8*)(xh + abase + (m >> 1) * S_ROW + (m & 1) * 128);
#pragma unroll
      for (int m = 0; m < 8; m++)
#pragma unroll
        for (int j = 0; j < 4; j++)
          acc[m][j] = __builtin_amdgcn_mfma_f32_16x16x32_f16(af[m], bcur[j], acc[m][j], 0, 0, 0);
#pragma unroll
      for (int j = 0; j < 4; j++) bcur[j] = bnxt[j];
    }
  }

  // ---- epilogue: BN + act, LDS transpose (reuse xh), coalesced 16B stores ----
  __syncthreads();   // other waves may still be reading xh halo
  _Float16* tb = xh + wave * EP_WAVE;
  const bool istanh = (wave == 0) || (wave == 3);
#pragma unroll 1
  for (int jp = 0; jp < 2; jp++) {
    // write phase: lane holds co = j*16+lw, spatial (m, quad, reg)
#pragma unroll
    for (int jj = 0; jj < 2; jj++) {
      const int j  = jp * 2 + jj;
      const int co = wave * 64 + j * 16 + lw;
      const float s  = gamma[co] * rsqrtf(var[co] + EPSV);
      const float bb = fmaf(-mean[co], s, beta[co]);
#pragma unroll
      for (int m = 0; m < 8; m++) {
        half4v hv;
#pragma unroll
        for (int reg = 0; reg < 4; reg++) {
          float v = fmaf(acc[m][j][reg], s, bb);
          float a;
          if (istanh) {
            float tt = __expf(-2.f * fabsf(v));
            float r  = (1.f - tt) * __builtin_amdgcn_rcpf(1.f + tt);
            a = copysignf(r, v);
          } else {
            a = __builtin_amdgcn_rcpf(1.f + __expf(-v));
          }
          hv[reg] = (_Float16)a;
        }
        const int w_l = (m & 1) * 16 + quad * 4;
        *(half4v*)(tb + (jj * 16 + lw) * EP_COSTRIDE + (m >> 1) * 32 + w_l) = hv;
      }
    }
    // read phase: lane -> (co_l, h, w8); one 16B store = full (co,h) 64B row with 3 peers
#pragma unroll
    for (int rr = 0; rr < 8; rr++) {
      const int co_l = rr * 4 + quad;
      const int h    = (lane >> 2) & 3;
      const int w8   = lane & 3;
      half8 v = *(const half8*)(tb + co_l * EP_COSTRIDE + h * 32 + w8 * 8);
      const int co = wave * 64 + jp * 32 + co_l;
      *(half8*)(gates + (size_t)co * DHW_ + d * HW_ + (h0 + h) * WW_ + w0 + w8 * 8) = v;
    }
  }
}

// -------- SRU-style recurrence over D, thread per 2x (c,h,w) (half2) --------
__global__ __launch_bounds__(256) void recurrence_k(const _Float16* __restrict__ gates,
                                                    float* __restrict__ out) {
  int idx = blockIdx.x * 256 + threadIdx.x;
  if (idx >= CI_ * HW_ / 2) return;
  int c  = idx / (HW_ / 2);
  int p2 = idx - c * (HW_ / 2);
  const _Float16* g0 = gates + (size_t)c * DHW_ + 2 * p2;
  const _Float16* gw = g0;                          // Wx (co 0..63)
  const _Float16* gf = g0 + (size_t)64 * DHW_;      // ft
  const _Float16* gr = g0 + (size_t)128 * DHW_;     // rt
  const _Float16* gx = g0 + (size_t)192 * DHW_;     // X
  float* op = out + (size_t)c * DHW_ + 2 * p2;

  half2v f0 = *(const half2v*)gf;
  half2v r0 = *(const half2v*)gr;
  half2v x0 = *(const half2v*)gx;
  float C[2];
  float2v o;
#pragma unroll
  for (int k = 0; k < 2; k++) {
    C[k] = 1.f - (float)f0[k];
    o[k] = fmaf((float)r0[k], C[k] - (float)x0[k], (float)x0[k]);
  }
  *(float2v*)op = o;
#pragma unroll 1
  for (int t = 1; t < DD_; t++) {
    half2v wv = *(const half2v*)(gw + (size_t)t * HW_);
    half2v fv = *(const half2v*)(gf + (size_t)t * HW_);
    half2v rv = *(const half2v*)(gr + (size_t)t * HW_);
    half2v xv = *(const half2v*)(gx + (size_t)t * HW_);
#pragma unroll
    for (int k = 0; k < 2; k++) {
      C[k] = fmaf((float)fv[k], C[k] - (float)wv[k], (float)wv[k]);
      o[k] = fmaf((float)rv[k], C[k] - (float)xv[k], (float)xv[k]);
    }
    *(float2v*)(op + (size_t)t * HW_) = o;
  }
}

extern "C" void kernel_launch(void* const* d_in, const int* in_sizes, int n_in,
                              void* d_out, int out_size, void* d_ws, size_t ws_size,
                              hipStream_t stream) {
  const float* x     = (const float*)d_in[0];
  const float* w     = (const float*)d_in[1];
  const float* gamma = (const float*)d_in[2];
  const float* beta  = (const float*)d_in[3];
  const float* mean  = (const float*)d_in[4];
  const float* var   = (const float*)d_in[5];
  float* out = (float*)d_out;

  // ws: [wr: 27*256*64 fp16 = 884736 B][align 256][gates: 256*285696 fp16]
  _Float16* wr    = (_Float16*)d_ws;
  _Float16* gates = (_Float16*)((char*)d_ws + ((27 * 256 * 64 * 2 + 255) & ~255));

  repack_w_k<<<(27 * 256 * 64 + 255) / 256, 256, 0, stream>>>(w, wr);

  dim3 gconv(72, DD_);
  conv_mfma_k<<<gconv, 256, 0, stream>>>(x, wr, gamma, beta, mean, var, gates);

  recurrence_k<<<(CI_ * HW_ / 2 + 255) / 256, 256, 0, stream>>>(gates, out);
}